// Round 6
// baseline (333.277 us; speedup 1.0000x reference)
//
#include <hip/hip_runtime.h>

typedef __attribute__((ext_vector_type(8))) __bf16 bf16x8;
typedef __attribute__((ext_vector_type(4))) float f32x4;

__device__ __forceinline__ unsigned short f2bf(float f) {
  __bf16 h = (__bf16)f;
  return __builtin_bit_cast(unsigned short, h);
}

__device__ __forceinline__ f32x4 mfma_bf16(bf16x8 a, bf16x8 b, f32x4 c) {
  return __builtin_amdgcn_mfma_f32_16x16x32_bf16(a, b, c, 0, 0, 0);
}

__device__ __forceinline__ void gload_lds16(const void* g, void* l) {
  __builtin_amdgcn_global_load_lds((const __attribute__((address_space(1))) void*)g,
                                   (__attribute__((address_space(3))) void*)l, 16, 0, 0);
}

// ---------------- conversion kernels ----------------

__global__ void cvt_f32_bf16(const float* __restrict__ in, unsigned short* __restrict__ out, int n4) {
  int i = blockIdx.x * blockDim.x + threadIdx.x;
  if (i < n4) {
    float4 v = reinterpret_cast<const float4*>(in)[i];
    ushort4 o;
    o.x = f2bf(v.x); o.y = f2bf(v.y); o.z = f2bf(v.z); o.w = f2bf(v.w);
    reinterpret_cast<ushort4*>(out)[i] = o;
  }
}

// 4 weight matrices in one launch: each 1048576 floats = 262144 float4
__global__ void cvt4_f32_bf16(const float* __restrict__ a, const float* __restrict__ b,
                              const float* __restrict__ c, const float* __restrict__ d,
                              unsigned short* __restrict__ oa, unsigned short* __restrict__ ob,
                              unsigned short* __restrict__ oc, unsigned short* __restrict__ od) {
  int i = blockIdx.x * blockDim.x + threadIdx.x;   // 1048576 total
  int which = i >> 18, j = i & 262143;
  const float* src = (which == 0) ? a : (which == 1) ? b : (which == 2) ? c : d;
  unsigned short* dst = (which == 0) ? oa : (which == 1) ? ob : (which == 2) ? oc : od;
  float4 v = reinterpret_cast<const float4*>(src)[j];
  ushort4 o;
  o.x = f2bf(v.x); o.y = f2bf(v.y); o.z = f2bf(v.z); o.w = f2bf(v.w);
  reinterpret_cast<ushort4*>(dst)[j] = o;
}

// er[128][2048] f32 -> ert[2048][128] bf16, LDS-tiled transpose
__global__ void er_transpose(const float* __restrict__ er, unsigned short* __restrict__ ert) {
  __shared__ float t[32][33];
  int w0 = blockIdx.x * 32, d0 = blockIdx.y * 32;
  int tx = threadIdx.x, ty = threadIdx.y;          // 32 x 8
#pragma unroll
  for (int i = 0; i < 4; ++i)
    t[ty + i * 8][tx] = er[(size_t)(d0 + ty + i * 8) * 2048 + w0 + tx];
  __syncthreads();
#pragma unroll
  for (int i = 0; i < 4; ++i)
    ert[(size_t)(w0 + ty + i * 8) * 128 + d0 + tx] = f2bf(t[tx][ty + i * 8]);
}

// ---------------- GEMM: C[MxN] = A[Mx1024] * Bt[Nx1024]^T + bias ----------------
// grid (32 Mtiles, 8 Ntiles). mode: 0 bf16 out, 1 bf16 band-transposed Vt, 2 f32 out.

__global__ __launch_bounds__(256, 2) void gemm_bt(
    const unsigned short* __restrict__ A,
    const unsigned short* __restrict__ Bt,
    const float* __restrict__ bias,
    void* __restrict__ C,
    int mode)
{
  __shared__ unsigned short lds[16896];
  unsigned short* Al = lds;
  unsigned short* Bl = lds + 4096;

  const int tid = threadIdx.x;
  const int lane = tid & 63, wid = tid >> 6;
  const int lr = lane & 15, lq = lane >> 4;
  const int wr = wid >> 1, wc = wid & 1;
  const int i0 = blockIdx.x * 128, j0 = blockIdx.y * 128;

  f32x4 acc[4][4] = {};

  const int srow = tid >> 2;
  const int scolb = (tid & 3) << 4;

  const char* Abase = (const char*)A + (size_t)(i0 + srow) * 2048 + scolb;
  const char* Bbase = (const char*)Bt + (size_t)(j0 + srow) * 2048 + scolb;

  for (int kt = 0; kt < 32; ++kt) {
    const int k0b = kt * 64;
    __syncthreads();
    gload_lds16(Abase + k0b,             (char*)Al + tid * 16);
    gload_lds16(Abase + k0b + 64 * 2048, (char*)Al + 4096 + tid * 16);
    gload_lds16(Bbase + k0b,             (char*)Bl + tid * 16);
    gload_lds16(Bbase + k0b + 64 * 2048, (char*)Bl + 4096 + tid * 16);
    __syncthreads();

    bf16x8 af[4], bfr[4];
#pragma unroll
    for (int m = 0; m < 4; ++m)
      af[m] = *(const bf16x8*)((const char*)Al + (wr * 64 + m * 16 + lr) * 64 + lq * 16);
#pragma unroll
    for (int n = 0; n < 4; ++n)
      bfr[n] = *(const bf16x8*)((const char*)Bl + (wc * 64 + n * 16 + lr) * 64 + lq * 16);
    __builtin_amdgcn_s_setprio(1);
#pragma unroll
    for (int m = 0; m < 4; ++m)
#pragma unroll
      for (int n = 0; n < 4; ++n)
        acc[m][n] = mfma_bf16(af[m], bfr[n], acc[m][n]);
    __builtin_amdgcn_s_setprio(0);
  }

  float bv[4];
#pragma unroll
  for (int n = 0; n < 4; ++n) bv[n] = bias[j0 + wc * 64 + n * 16 + lr];

  if (mode == 1) {
    __syncthreads();
#pragma unroll
    for (int m = 0; m < 4; ++m)
#pragma unroll
      for (int n = 0; n < 4; ++n)
#pragma unroll
        for (int r = 0; r < 4; ++r) {
          int il = wr * 64 + m * 16 + lq * 4 + r;
          int jl = wc * 64 + n * 16 + lr;
          lds[jl * 132 + il] = f2bf(acc[m][n][r] + bv[n]);
        }
    __syncthreads();
    const int b = i0 >> 11, w0 = i0 & 2047, bd = j0 >> 7;
    unsigned short* out = (unsigned short*)C;
    for (int idx = tid; idx < 16384; idx += 256) {
      int dl = idx >> 7, wl = idx & 127;
      out[(size_t)((b * 8 + bd) * 128 + dl) * 2048 + w0 + wl] = lds[dl * 132 + wl];
    }
  } else if (mode == 0) {
    unsigned short* out = (unsigned short*)C;
#pragma unroll
    for (int m = 0; m < 4; ++m)
#pragma unroll
      for (int n = 0; n < 4; ++n)
#pragma unroll
        for (int r = 0; r < 4; ++r) {
          int gi = i0 + wr * 64 + m * 16 + lq * 4 + r;
          int gj = j0 + wc * 64 + n * 16 + lr;
          out[(size_t)gi * 1024 + gj] = f2bf(acc[m][n][r] + bv[n]);
        }
  } else {
    float* out = (float*)C;
#pragma unroll
    for (int m = 0; m < 4; ++m)
#pragma unroll
      for (int n = 0; n < 4; ++n)
#pragma unroll
        for (int r = 0; r < 4; ++r) {
          int gi = i0 + wr * 64 + m * 16 + lq * 4 + r;
          int gj = j0 + wc * 64 + n * 16 + lr;
          out[(size_t)gi * 1024 + gj] = acc[m][n][r] + bv[n];
        }
  }
}

// ---------------- fused attention ----------------
// QBLK=64, KVBLK=64. grid (16 = b*8+band, 32 qtiles) -> 512 blocks, 2/CU.
// 256 threads (4 waves x 16 q-rows). LDS 64KB+ total.

__global__ __launch_bounds__(256) void attn_fused(
    const unsigned short* __restrict__ Qb,
    const unsigned short* __restrict__ Kb,
    const unsigned short* __restrict__ Vt,
    const unsigned short* __restrict__ ErT,
    float* __restrict__ a_out,
    unsigned short* __restrict__ ctx)
{
  __shared__ __align__(16) char Klb[16384];  // K[kj] [64][256B] swz
  __shared__ __align__(16) char Qlb[16384];  // Q[kj] [64][256B] swz
  __shared__ __align__(16) char Vlb[16384];  // Vt    [128][128B] swz
  __shared__ __align__(16) char Plb[8192];   // P     [64][128B] swz
  __shared__ __align__(16) char Alb[8192];   // a repack, 2KB per wave

  const int bb = blockIdx.x;                 // b*8+band
  const int bd = bb & 7, b = bb >> 3;
  const int qi0 = blockIdx.y * 64;
  const int tid = threadIdx.x, wid = tid >> 6, lane = tid & 63;
  const int lr = lane & 15, lq = lane >> 4;

  // persistent A-fragments: Q[qi] and ErT[qi] rows (d=128 -> 4 k-slices)
  bf16x8 qf[4], ef[4];
  {
    const unsigned short* Qrow = Qb + (size_t)(b * 2048 + qi0 + wid * 16 + lr) * 1024 + bd * 128;
    const unsigned short* Erow = ErT + (size_t)(qi0 + wid * 16 + lr) * 128;
#pragma unroll
    for (int kk = 0; kk < 4; ++kk) {
      qf[kk] = *(const bf16x8*)(Qrow + kk * 32 + lq * 8);
      ef[kk] = *(const bf16x8*)(Erow + kk * 32 + lq * 8);
    }
  }

  // staging geometry: K/Q 16KB each (64 rows x 256B), V 16KB (128 rows x 128B)
  int dstKQ[4], dstV[4];
  const char *ksrc[4], *qsrc[4], *vsrc[4];
#pragma unroll
  for (int p = 0; p < 4; ++p) {
    int lin = (p * 256 + tid) * 16;
    int rKQ = lin >> 8, cKQ = lin & 255;
    dstKQ[p] = rKQ * 256 + (cKQ ^ ((rKQ & 7) << 4));
    ksrc[p] = (const char*)Kb + ((size_t)(b * 2048 + rKQ) * 1024 + bd * 128) * 2 + cKQ;
    qsrc[p] = (const char*)Qb + ((size_t)(b * 2048 + rKQ) * 1024 + bd * 128) * 2 + cKQ;
    int rV = lin >> 7, cV = lin & 127;
    dstV[p] = rV * 128 + (cV ^ ((rV & 7) << 4));
    vsrc[p] = (const char*)Vt + ((size_t)(bb * 128 + rV) * 2048) * 2 + cV;
  }

  // prefetch tile 0
  uint4 rk[4], rq[4], rv[4];
#pragma unroll
  for (int p = 0; p < 4; ++p) {
    rk[p] = *(const uint4*)(ksrc[p]);
    rq[p] = *(const uint4*)(qsrc[p]);
    rv[p] = *(const uint4*)(vsrc[p]);
  }

  f32x4 oacc[8] = {};
  float M[4], L[4];
#pragma unroll
  for (int r = 0; r < 4; ++r) { M[r] = -1e30f; L[r] = 0.f; }

  float* abase = a_out + (size_t)bb * 2048 * 2048;

  for (int kt = 0; kt < 32; ++kt) {
    const int kj0 = kt * 64;
    __syncthreads();
#pragma unroll
    for (int p = 0; p < 4; ++p) {
      *(uint4*)(Klb + dstKQ[p]) = rk[p];
      *(uint4*)(Qlb + dstKQ[p]) = rq[p];
      *(uint4*)(Vlb + dstV[p]) = rv[p];
    }
    if (kt < 31) {
      const size_t kqoff = (size_t)(kt + 1) * 131072;   // +64 rows * 2048B
      const size_t voff = (size_t)(kt + 1) * 128;       // +64 cols * 2B
#pragma unroll
      for (int p = 0; p < 4; ++p) {
        rk[p] = *(const uint4*)(ksrc[p] + kqoff);
        rq[p] = *(const uint4*)(qsrc[p] + kqoff);
        rv[p] = *(const uint4*)(vsrc[p] + voff);
      }
    }
    __syncthreads();

    // S = Q·K^T + ErT·Qk^T  (4 nf-fragments of 16 kv cols)
    f32x4 sacc[4] = {};
    __builtin_amdgcn_s_setprio(1);
#pragma unroll
    for (int kk = 0; kk < 4; ++kk) {
#pragma unroll
      for (int nf = 0; nf < 4; ++nf) {
        const int row = nf * 16 + lr;
        bf16x8 kf = *(const bf16x8*)(Klb + row * 256 + ((kk * 64 + lq * 16) ^ ((row & 7) << 4)));
        sacc[nf] = mfma_bf16(qf[kk], kf, sacc[nf]);
      }
#pragma unroll
      for (int nf = 0; nf < 4; ++nf) {
        const int row = nf * 16 + lr;
        bf16x8 qkf = *(const bf16x8*)(Qlb + row * 256 + ((kk * 64 + lq * 16) ^ ((row & 7) << 4)));
        sacc[nf] = mfma_bf16(ef[kk], qkf, sacc[nf]);
      }
    }
    __builtin_amdgcn_s_setprio(0);

#pragma unroll
    for (int nf = 0; nf < 4; ++nf)
#pragma unroll
      for (int r = 0; r < 4; ++r) sacc[nf][r] *= 0.03125f;

    // emit `a`: wave-local repack to full 128B lines, through L2 (write-back
    // merges fully-covered lines; nt caused 2x HBM write amplification)
    {
      char* aw = Alb + wid * 2048;
#pragma unroll
      for (int h = 0; h < 2; ++h) {
#pragma unroll
        for (int nf2 = 0; nf2 < 2; ++nf2)
#pragma unroll
          for (int r = 0; r < 4; ++r) {
            const int row = lq * 4 + r;
            const int col = nf2 * 16 + lr;
            *(float*)(aw + row * 128 + ((col * 4) ^ (((row >> 2) & 1) << 6))) =
                sacc[h * 2 + nf2][r];
          }
#pragma unroll
        for (int it = 0; it < 2; ++it) {
          const int idx = it * 64 + lane;
          const int rowl = idx >> 3, c16 = idx & 7;
          f32x4 v = *(f32x4*)(aw + rowl * 128 + ((c16 * 16) ^ (((rowl >> 2) & 1) << 6)));
          *(f32x4*)(abase + (size_t)(qi0 + wid * 16 + rowl) * 2048 + kj0 + h * 32 + c16 * 4) = v;
        }
      }
    }

    // online softmax
    float rmax[4];
#pragma unroll
    for (int r = 0; r < 4; ++r) {
      float m0 = fmaxf(fmaxf(sacc[0][r], sacc[1][r]), fmaxf(sacc[2][r], sacc[3][r]));
      m0 = fmaxf(m0, __shfl_xor(m0, 1));
      m0 = fmaxf(m0, __shfl_xor(m0, 2));
      m0 = fmaxf(m0, __shfl_xor(m0, 4));
      m0 = fmaxf(m0, __shfl_xor(m0, 8));
      rmax[r] = m0;
    }
    bool small = (rmax[0] - M[0] <= 8.f) & (rmax[1] - M[1] <= 8.f) &
                 (rmax[2] - M[2] <= 8.f) & (rmax[3] - M[3] <= 8.f);
    unsigned long long vote = __ballot(small);
    if (vote != ~0ull) {                      // rescale path
      float scl[4];
#pragma unroll
      for (int r = 0; r < 4; ++r) {
        float Mn = fmaxf(M[r], rmax[r]);
        scl[r] = __expf(M[r] - Mn);
        M[r] = Mn;
        L[r] *= scl[r];
      }
#pragma unroll
      for (int dn = 0; dn < 8; ++dn)
#pragma unroll
        for (int r = 0; r < 4; ++r) oacc[dn][r] *= scl[r];
    }
    float rsum[4] = {0.f, 0.f, 0.f, 0.f};
#pragma unroll
    for (int nf = 0; nf < 4; ++nf)
#pragma unroll
      for (int r = 0; r < 4; ++r) {
        float pv = __expf(sacc[nf][r] - M[r]);
        sacc[nf][r] = pv;
        rsum[r] += pv;
      }
    // P -> LDS (bf16), wave-local rows, swizzled
    {
      const int prow0 = wid * 16 + lq * 4;
#pragma unroll
      for (int nf = 0; nf < 4; ++nf)
#pragma unroll
        for (int r = 0; r < 4; ++r) {
          const int row = prow0 + r;
          *(unsigned short*)(Plb + row * 128 + (((nf * 16 + lr) * 2) ^ ((row & 7) << 4))) =
              f2bf(sacc[nf][r]);
        }
    }
#pragma unroll
    for (int r = 0; r < 4; ++r) {
      rsum[r] += __shfl_xor(rsum[r], 1);
      rsum[r] += __shfl_xor(rsum[r], 2);
      rsum[r] += __shfl_xor(rsum[r], 4);
      rsum[r] += __shfl_xor(rsum[r], 8);
      L[r] += rsum[r];
    }

    // O += P · V
    __builtin_amdgcn_s_setprio(1);
#pragma unroll
    for (int kk = 0; kk < 2; ++kk) {
      const int prow = wid * 16 + lr;
      bf16x8 pf = *(const bf16x8*)(Plb + prow * 128 + ((kk * 64 + lq * 16) ^ ((prow & 7) << 4)));
#pragma unroll
      for (int dn = 0; dn < 8; ++dn) {
        const int vrow = dn * 16 + lr;
        bf16x8 vf = *(const bf16x8*)(Vlb + vrow * 128 + ((kk * 64 + lq * 16) ^ ((vrow & 7) << 4)));
        oacc[dn] = mfma_bf16(pf, vf, oacc[dn]);
      }
    }
    __builtin_amdgcn_s_setprio(0);
  }

  // epilogue: ctx = O / L -> bf16 [b*2048+w][bd*128+d]
  {
    const int qrow_base = b * 2048 + qi0 + wid * 16 + lq * 4;
#pragma unroll
    for (int dn = 0; dn < 8; ++dn)
#pragma unroll
      for (int r = 0; r < 4; ++r) {
        float v = oacc[dn][r] / L[r];
        ctx[(size_t)(qrow_base + r) * 1024 + bd * 128 + dn * 16 + lr] = f2bf(v);
      }
  }
}

// ---------------- launch ----------------

extern "C" void kernel_launch(void* const* d_in, const int* in_sizes, int n_in,
                              void* d_out, int out_size, void* d_ws, size_t ws_size,
                              hipStream_t stream) {
  const float* x  = (const float*)d_in[0];
  const float* Wq = (const float*)d_in[1];
  const float* bq = (const float*)d_in[2];
  const float* Wk = (const float*)d_in[3];
  const float* bk = (const float*)d_in[4];
  const float* Wv = (const float*)d_in[5];
  const float* bv = (const float*)d_in[6];
  const float* Wo = (const float*)d_in[7];
  const float* bo = (const float*)d_in[8];
  const float* er = (const float*)d_in[9];

  char* ws = (char*)d_ws;
  unsigned short* xb  = (unsigned short*)(ws + 0);          //  8 MB
  unsigned short* Wqb = (unsigned short*)(ws + 8388608);    //  2 MB
  unsigned short* Wkb = (unsigned short*)(ws + 10485760);   //  2 MB
  unsigned short* Wvb = (unsigned short*)(ws + 12582912);   //  2 MB
  unsigned short* Wob = (unsigned short*)(ws + 14680064);   //  2 MB
  unsigned short* Qb  = (unsigned short*)(ws + 16777216);   //  8 MB
  unsigned short* Kb  = (unsigned short*)(ws + 25165824);   //  8 MB
  unsigned short* Vtb = (unsigned short*)(ws + 33554432);   //  8 MB [16][128][2048]
  unsigned short* ctx = (unsigned short*)(ws + 41943040);   //  8 MB
  unsigned short* ert = (unsigned short*)(ws + 50331648);   //  0.5 MB [2048][128]

  float* a_out = (float*)d_out + 4194304;

  cvt_f32_bf16<<<dim3(4096), dim3(256), 0, stream>>>(x, xb, 1048576);
  cvt4_f32_bf16<<<dim3(4096), dim3(256), 0, stream>>>(Wq, Wk, Wv, Wo, Wqb, Wkb, Wvb, Wob);
  er_transpose<<<dim3(64, 4), dim3(32, 8), 0, stream>>>(er, ert);

  gemm_bt<<<dim3(32, 8), dim3(256), 0, stream>>>(xb, Wqb, bq, (void*)Qb, 0);
  gemm_bt<<<dim3(32, 8), dim3(256), 0, stream>>>(xb, Wkb, bk, (void*)Kb, 0);
  gemm_bt<<<dim3(32, 8), dim3(256), 0, stream>>>(xb, Wvb, bv, (void*)Vtb, 1);

  attn_fused<<<dim3(16, 32), dim3(256), 0, stream>>>(Qb, Kb, Vtb, ert, a_out, ctx);

  gemm_bt<<<dim3(32, 8), dim3(256), 0, stream>>>(ctx, Wob, bo, d_out, 2);
}

// Round 7
// 290.852 us; speedup vs baseline: 1.1459x; 1.1459x over previous
//
#include <hip/hip_runtime.h>

typedef __attribute__((ext_vector_type(8))) __bf16 bf16x8;
typedef __attribute__((ext_vector_type(4))) float f32x4;

__device__ __forceinline__ unsigned short f2bf(float f) {
  __bf16 h = (__bf16)f;
  return __builtin_bit_cast(unsigned short, h);
}

__device__ __forceinline__ f32x4 mfma_bf16(bf16x8 a, bf16x8 b, f32x4 c) {
  return __builtin_amdgcn_mfma_f32_16x16x32_bf16(a, b, c, 0, 0, 0);
}

__device__ __forceinline__ void gload_lds16(const void* g, void* l) {
  __builtin_amdgcn_global_load_lds((const __attribute__((address_space(1))) void*)g,
                                   (__attribute__((address_space(3))) void*)l, 16, 0, 0);
}

// ---------------- conversion kernels ----------------

__global__ void cvt_f32_bf16(const float* __restrict__ in, unsigned short* __restrict__ out, int n4) {
  int i = blockIdx.x * blockDim.x + threadIdx.x;
  if (i < n4) {
    float4 v = reinterpret_cast<const float4*>(in)[i];
    ushort4 o;
    o.x = f2bf(v.x); o.y = f2bf(v.y); o.z = f2bf(v.z); o.w = f2bf(v.w);
    reinterpret_cast<ushort4*>(out)[i] = o;
  }
}

// 4 weight matrices in one launch: each 1048576 floats = 262144 float4
__global__ void cvt4_f32_bf16(const float* __restrict__ a, const float* __restrict__ b,
                              const float* __restrict__ c, const float* __restrict__ d,
                              unsigned short* __restrict__ oa, unsigned short* __restrict__ ob,
                              unsigned short* __restrict__ oc, unsigned short* __restrict__ od) {
  int i = blockIdx.x * blockDim.x + threadIdx.x;   // 1048576 total
  int which = i >> 18, j = i & 262143;
  const float* src = (which == 0) ? a : (which == 1) ? b : (which == 2) ? c : d;
  unsigned short* dst = (which == 0) ? oa : (which == 1) ? ob : (which == 2) ? oc : od;
  float4 v = reinterpret_cast<const float4*>(src)[j];
  ushort4 o;
  o.x = f2bf(v.x); o.y = f2bf(v.y); o.z = f2bf(v.z); o.w = f2bf(v.w);
  reinterpret_cast<ushort4*>(dst)[j] = o;
}

// er[128][2048] f32 -> ert[2048][128] bf16, LDS-tiled transpose
__global__ void er_transpose(const float* __restrict__ er, unsigned short* __restrict__ ert) {
  __shared__ float t[32][33];
  int w0 = blockIdx.x * 32, d0 = blockIdx.y * 32;
  int tx = threadIdx.x, ty = threadIdx.y;          // 32 x 8
#pragma unroll
  for (int i = 0; i < 4; ++i)
    t[ty + i * 8][tx] = er[(size_t)(d0 + ty + i * 8) * 2048 + w0 + tx];
  __syncthreads();
#pragma unroll
  for (int i = 0; i < 4; ++i)
    ert[(size_t)(w0 + ty + i * 8) * 128 + d0 + tx] = f2bf(t[tx][ty + i * 8]);
}

// ---------------- GEMM: C[MxN] = A[Mx1024] * Bt[Nx1024]^T + bias ----------------
// grid (32 Mtiles, 8 Ntiles). mode: 0 bf16 out, 1 bf16 band-transposed Vt, 2 f32 out.

__global__ __launch_bounds__(256, 2) void gemm_bt(
    const unsigned short* __restrict__ A,
    const unsigned short* __restrict__ Bt,
    const float* __restrict__ bias,
    void* __restrict__ C,
    int mode)
{
  __shared__ unsigned short lds[16896];
  unsigned short* Al = lds;
  unsigned short* Bl = lds + 4096;

  const int tid = threadIdx.x;
  const int lane = tid & 63, wid = tid >> 6;
  const int lr = lane & 15, lq = lane >> 4;
  const int wr = wid >> 1, wc = wid & 1;
  const int i0 = blockIdx.x * 128, j0 = blockIdx.y * 128;

  f32x4 acc[4][4] = {};

  const int srow = tid >> 2;
  const int scolb = (tid & 3) << 4;

  const char* Abase = (const char*)A + (size_t)(i0 + srow) * 2048 + scolb;
  const char* Bbase = (const char*)Bt + (size_t)(j0 + srow) * 2048 + scolb;

  for (int kt = 0; kt < 32; ++kt) {
    const int k0b = kt * 64;
    __syncthreads();
    gload_lds16(Abase + k0b,             (char*)Al + tid * 16);
    gload_lds16(Abase + k0b + 64 * 2048, (char*)Al + 4096 + tid * 16);
    gload_lds16(Bbase + k0b,             (char*)Bl + tid * 16);
    gload_lds16(Bbase + k0b + 64 * 2048, (char*)Bl + 4096 + tid * 16);
    __syncthreads();

    bf16x8 af[4], bfr[4];
#pragma unroll
    for (int m = 0; m < 4; ++m)
      af[m] = *(const bf16x8*)((const char*)Al + (wr * 64 + m * 16 + lr) * 64 + lq * 16);
#pragma unroll
    for (int n = 0; n < 4; ++n)
      bfr[n] = *(const bf16x8*)((const char*)Bl + (wc * 64 + n * 16 + lr) * 64 + lq * 16);
    __builtin_amdgcn_s_setprio(1);
#pragma unroll
    for (int m = 0; m < 4; ++m)
#pragma unroll
      for (int n = 0; n < 4; ++n)
        acc[m][n] = mfma_bf16(af[m], bfr[n], acc[m][n]);
    __builtin_amdgcn_s_setprio(0);
  }

  float bv[4];
#pragma unroll
  for (int n = 0; n < 4; ++n) bv[n] = bias[j0 + wc * 64 + n * 16 + lr];

  if (mode == 1) {
    __syncthreads();
#pragma unroll
    for (int m = 0; m < 4; ++m)
#pragma unroll
      for (int n = 0; n < 4; ++n)
#pragma unroll
        for (int r = 0; r < 4; ++r) {
          int il = wr * 64 + m * 16 + lq * 4 + r;
          int jl = wc * 64 + n * 16 + lr;
          lds[jl * 132 + il] = f2bf(acc[m][n][r] + bv[n]);
        }
    __syncthreads();
    const int b = i0 >> 11, w0 = i0 & 2047, bd = j0 >> 7;
    unsigned short* out = (unsigned short*)C;
    for (int idx = tid; idx < 16384; idx += 256) {
      int dl = idx >> 7, wl = idx & 127;
      out[(size_t)((b * 8 + bd) * 128 + dl) * 2048 + w0 + wl] = lds[dl * 132 + wl];
    }
  } else if (mode == 0) {
    unsigned short* out = (unsigned short*)C;
#pragma unroll
    for (int m = 0; m < 4; ++m)
#pragma unroll
      for (int n = 0; n < 4; ++n)
#pragma unroll
        for (int r = 0; r < 4; ++r) {
          int gi = i0 + wr * 64 + m * 16 + lq * 4 + r;
          int gj = j0 + wc * 64 + n * 16 + lr;
          out[(size_t)gi * 1024 + gj] = f2bf(acc[m][n][r] + bv[n]);
        }
  } else {
    float* out = (float*)C;
#pragma unroll
    for (int m = 0; m < 4; ++m)
#pragma unroll
      for (int n = 0; n < 4; ++n)
#pragma unroll
        for (int r = 0; r < 4; ++r) {
          int gi = i0 + wr * 64 + m * 16 + lq * 4 + r;
          int gj = j0 + wc * 64 + n * 16 + lr;
          out[(size_t)gi * 1024 + gj] = acc[m][n][r] + bv[n];
        }
  }
}

// ---------------- fused attention ----------------
// 128x128 tiles (>=512B of each a-row per iteration -> no HBM write
// amplification, measured R1). grid (16 = b*8+band, 16 qtiles),
// 512 threads (8 waves x 16 q-rows). Plain scalar a-stores through L2.

__global__ __launch_bounds__(512) void attn_fused(
    const unsigned short* __restrict__ Qb,
    const unsigned short* __restrict__ Kb,
    const unsigned short* __restrict__ Vt,
    const unsigned short* __restrict__ ErT,
    float* __restrict__ a_out,
    unsigned short* __restrict__ ctx)
{
  __shared__ __align__(16) char Klb[32768];  // K[kj] [128][256B] swz
  __shared__ __align__(16) char Qlb[32768];  // Q[kj] [128][256B] swz
  __shared__ __align__(16) char Vlb[32768];  // Vt    [128][256B] swz
  __shared__ __align__(16) char Plb[32768];  // P     [128][256B] swz

  const int bb = blockIdx.x;                 // b*8+band
  const int bd = bb & 7, b = bb >> 3;
  const int qi0 = blockIdx.y * 128;
  const int tid = threadIdx.x, wid = tid >> 6, lane = tid & 63;
  const int lr = lane & 15, lq = lane >> 4;

  // persistent A-fragments: Q[qi] and ErT[qi] rows (d=128 -> 4 k-slices)
  bf16x8 qf[4], ef[4];
  {
    const unsigned short* Qrow = Qb + (size_t)(b * 2048 + qi0 + wid * 16 + lr) * 1024 + bd * 128;
    const unsigned short* Erow = ErT + (size_t)(qi0 + wid * 16 + lr) * 128;
#pragma unroll
    for (int kk = 0; kk < 4; ++kk) {
      qf[kk] = *(const bf16x8*)(Qrow + kk * 32 + lq * 8);
      ef[kk] = *(const bf16x8*)(Erow + kk * 32 + lq * 8);
    }
  }

  // staging geometry: 3 tiles x 32KB, 512 thr x 4 x 16B
  int dsto[4];
  const char *ksrc[4], *qsrc[4], *vsrc[4];
#pragma unroll
  for (int p = 0; p < 4; ++p) {
    int lin = (p * 512 + tid) * 16;
    int row = lin >> 8, colb = lin & 255;
    dsto[p] = row * 256 + (colb ^ ((row & 7) << 4));
    ksrc[p] = (const char*)Kb + ((size_t)(b * 2048 + row) * 1024 + bd * 128) * 2 + colb;
    qsrc[p] = (const char*)Qb + ((size_t)(b * 2048 + row) * 1024 + bd * 128) * 2 + colb;
    vsrc[p] = (const char*)Vt + ((size_t)(bb * 128 + row) * 2048) * 2 + colb;
  }

  // prefetch tile 0
  uint4 rk[4], rq[4], rv[4];
#pragma unroll
  for (int p = 0; p < 4; ++p) {
    rk[p] = *(const uint4*)(ksrc[p]);
    rq[p] = *(const uint4*)(qsrc[p]);
    rv[p] = *(const uint4*)(vsrc[p]);
  }

  f32x4 oacc[8] = {};
  float M[4], L[4];
#pragma unroll
  for (int r = 0; r < 4; ++r) { M[r] = -1e30f; L[r] = 0.f; }

  float* abase = a_out + (size_t)bb * 2048 * 2048;

  for (int kt = 0; kt < 16; ++kt) {
    const int kj0 = kt * 128;
    __syncthreads();
#pragma unroll
    for (int p = 0; p < 4; ++p) {
      *(uint4*)(Klb + dsto[p]) = rk[p];
      *(uint4*)(Qlb + dsto[p]) = rq[p];
      *(uint4*)(Vlb + dsto[p]) = rv[p];
    }
    if (kt < 15) {
      const size_t kqoff = (size_t)(kt + 1) * 262144;   // +128 rows * 2048B
      const size_t voff = (size_t)(kt + 1) * 256;       // +128 cols * 2B
#pragma unroll
      for (int p = 0; p < 4; ++p) {
        rk[p] = *(const uint4*)(ksrc[p] + kqoff);
        rq[p] = *(const uint4*)(qsrc[p] + kqoff);
        rv[p] = *(const uint4*)(vsrc[p] + voff);
      }
    }
    __syncthreads();

    // S = Q·K^T + ErT·Qk^T  (8 nf-fragments of 16 kv cols)
    f32x4 sacc[8] = {};
    __builtin_amdgcn_s_setprio(1);
#pragma unroll
    for (int kk = 0; kk < 4; ++kk) {
#pragma unroll
      for (int nf = 0; nf < 8; ++nf) {
        const int row = nf * 16 + lr;
        bf16x8 kf = *(const bf16x8*)(Klb + row * 256 + ((kk * 64 + lq * 16) ^ ((row & 7) << 4)));
        sacc[nf] = mfma_bf16(qf[kk], kf, sacc[nf]);
      }
#pragma unroll
      for (int nf = 0; nf < 8; ++nf) {
        const int row = nf * 16 + lr;
        bf16x8 qkf = *(const bf16x8*)(Qlb + row * 256 + ((kk * 64 + lq * 16) ^ ((row & 7) << 4)));
        sacc[nf] = mfma_bf16(ef[kk], qkf, sacc[nf]);
      }
    }
    __builtin_amdgcn_s_setprio(0);

    // scale by 1/sqrt(1024) and emit `a`: plain scalar stores through L2
    // (512B/row/iter fully covered in one burst -> no write amplification)
#pragma unroll
    for (int nf = 0; nf < 8; ++nf)
#pragma unroll
      for (int r = 0; r < 4; ++r) sacc[nf][r] *= 0.03125f;
    {
      const int qrow_base = qi0 + wid * 16 + lq * 4;
#pragma unroll
      for (int nf = 0; nf < 8; ++nf)
#pragma unroll
        for (int r = 0; r < 4; ++r)
          abase[(size_t)(qrow_base + r) * 2048 + kj0 + nf * 16 + lr] = sacc[nf][r];
    }

    // online softmax with defer-max (skip O-rescale when max growth <= 8)
    float rmax[4];
#pragma unroll
    for (int r = 0; r < 4; ++r) {
      float m0 = sacc[0][r];
#pragma unroll
      for (int nf = 1; nf < 8; ++nf) m0 = fmaxf(m0, sacc[nf][r]);
      m0 = fmaxf(m0, __shfl_xor(m0, 1));
      m0 = fmaxf(m0, __shfl_xor(m0, 2));
      m0 = fmaxf(m0, __shfl_xor(m0, 4));
      m0 = fmaxf(m0, __shfl_xor(m0, 8));
      rmax[r] = m0;
    }
    bool small = (rmax[0] - M[0] <= 8.f) & (rmax[1] - M[1] <= 8.f) &
                 (rmax[2] - M[2] <= 8.f) & (rmax[3] - M[3] <= 8.f);
    unsigned long long vote = __ballot(small);
    if (vote != ~0ull) {                      // rescale path
      float scl[4];
#pragma unroll
      for (int r = 0; r < 4; ++r) {
        float Mn = fmaxf(M[r], rmax[r]);
        scl[r] = __expf(M[r] - Mn);
        M[r] = Mn;
        L[r] *= scl[r];
      }
#pragma unroll
      for (int dn = 0; dn < 8; ++dn)
#pragma unroll
        for (int r = 0; r < 4; ++r) oacc[dn][r] *= scl[r];
    }
    float rsum[4] = {0.f, 0.f, 0.f, 0.f};
#pragma unroll
    for (int nf = 0; nf < 8; ++nf)
#pragma unroll
      for (int r = 0; r < 4; ++r) {
        float pv = __expf(sacc[nf][r] - M[r]);
        sacc[nf][r] = pv;
        rsum[r] += pv;
      }
    // P -> LDS (bf16), wave-local rows, swizzled
    {
      const int prow0 = wid * 16 + lq * 4;
#pragma unroll
      for (int nf = 0; nf < 8; ++nf)
#pragma unroll
        for (int r = 0; r < 4; ++r) {
          const int row = prow0 + r;
          *(unsigned short*)(Plb + row * 256 + (((nf * 16 + lr) * 2) ^ ((row & 7) << 4))) =
              f2bf(sacc[nf][r]);
        }
    }
#pragma unroll
    for (int r = 0; r < 4; ++r) {
      rsum[r] += __shfl_xor(rsum[r], 1);
      rsum[r] += __shfl_xor(rsum[r], 2);
      rsum[r] += __shfl_xor(rsum[r], 4);
      rsum[r] += __shfl_xor(rsum[r], 8);
      L[r] += rsum[r];
    }

    // O += P · V
    __builtin_amdgcn_s_setprio(1);
#pragma unroll
    for (int kk = 0; kk < 4; ++kk) {
      const int prow = wid * 16 + lr;
      bf16x8 pf = *(const bf16x8*)(Plb + prow * 256 + ((kk * 64 + lq * 16) ^ ((prow & 7) << 4)));
#pragma unroll
      for (int dn = 0; dn < 8; ++dn) {
        const int vrow = dn * 16 + lr;
        bf16x8 vf = *(const bf16x8*)(Vlb + vrow * 256 + ((kk * 64 + lq * 16) ^ ((vrow & 7) << 4)));
        oacc[dn] = mfma_bf16(pf, vf, oacc[dn]);
      }
    }
    __builtin_amdgcn_s_setprio(0);
  }

  // epilogue: ctx = O / L -> bf16 [b*2048+w][bd*128+d]
  {
    const int qrow_base = b * 2048 + qi0 + wid * 16 + lq * 4;
#pragma unroll
    for (int dn = 0; dn < 8; ++dn)
#pragma unroll
      for (int r = 0; r < 4; ++r) {
        float v = oacc[dn][r] / L[r];
        ctx[(size_t)(qrow_base + r) * 1024 + bd * 128 + dn * 16 + lr] = f2bf(v);
      }
  }
}

// ---------------- launch ----------------

extern "C" void kernel_launch(void* const* d_in, const int* in_sizes, int n_in,
                              void* d_out, int out_size, void* d_ws, size_t ws_size,
                              hipStream_t stream) {
  const float* x  = (const float*)d_in[0];
  const float* Wq = (const float*)d_in[1];
  const float* bq = (const float*)d_in[2];
  const float* Wk = (const float*)d_in[3];
  const float* bk = (const float*)d_in[4];
  const float* Wv = (const float*)d_in[5];
  const float* bv = (const float*)d_in[6];
  const float* Wo = (const float*)d_in[7];
  const float* bo = (const float*)d_in[8];
  const float* er = (const float*)d_in[9];

  char* ws = (char*)d_ws;
  unsigned short* xb  = (unsigned short*)(ws + 0);          //  8 MB
  unsigned short* Wqb = (unsigned short*)(ws + 8388608);    //  2 MB
  unsigned short* Wkb = (unsigned short*)(ws + 10485760);   //  2 MB
  unsigned short* Wvb = (unsigned short*)(ws + 12582912);   //  2 MB
  unsigned short* Wob = (unsigned short*)(ws + 14680064);   //  2 MB
  unsigned short* Qb  = (unsigned short*)(ws + 16777216);   //  8 MB
  unsigned short* Kb  = (unsigned short*)(ws + 25165824);   //  8 MB
  unsigned short* Vtb = (unsigned short*)(ws + 33554432);   //  8 MB [16][128][2048]
  unsigned short* ctx = (unsigned short*)(ws + 41943040);   //  8 MB
  unsigned short* ert = (unsigned short*)(ws + 50331648);   //  0.5 MB [2048][128]

  float* a_out = (float*)d_out + 4194304;

  cvt_f32_bf16<<<dim3(4096), dim3(256), 0, stream>>>(x, xb, 1048576);
  cvt4_f32_bf16<<<dim3(4096), dim3(256), 0, stream>>>(Wq, Wk, Wv, Wo, Wqb, Wkb, Wvb, Wob);
  er_transpose<<<dim3(64, 4), dim3(32, 8), 0, stream>>>(er, ert);

  gemm_bt<<<dim3(32, 8), dim3(256), 0, stream>>>(xb, Wqb, bq, (void*)Qb, 0);
  gemm_bt<<<dim3(32, 8), dim3(256), 0, stream>>>(xb, Wkb, bk, (void*)Kb, 0);
  gemm_bt<<<dim3(32, 8), dim3(256), 0, stream>>>(xb, Wvb, bv, (void*)Vtb, 1);

  attn_fused<<<dim3(16, 16), dim3(512), 0, stream>>>(Qb, Kb, Vtb, ert, a_out, ctx);

  gemm_bt<<<dim3(32, 8), dim3(256), 0, stream>>>(ctx, Wob, bo, d_out, 2);
}

// Round 8
// 187.238 us; speedup vs baseline: 1.7800x; 1.5534x over previous
//
#include <hip/hip_runtime.h>

typedef __attribute__((ext_vector_type(8))) __bf16 bf16x8;
typedef __attribute__((ext_vector_type(4))) float f32x4;

__device__ __forceinline__ unsigned short f2bf(float f) {
  __bf16 h = (__bf16)f;
  return __builtin_bit_cast(unsigned short, h);
}

__device__ __forceinline__ f32x4 mfma_bf16(bf16x8 a, bf16x8 b, f32x4 c) {
  return __builtin_amdgcn_mfma_f32_16x16x32_bf16(a, b, c, 0, 0, 0);
}

__device__ __forceinline__ void gload_lds16(const void* g, void* l) {
  __builtin_amdgcn_global_load_lds((const __attribute__((address_space(1))) void*)g,
                                   (__attribute__((address_space(3))) void*)l, 16, 0, 0);
}

// ---------------- conversion kernels ----------------

__global__ void cvt_f32_bf16(const float* __restrict__ in, unsigned short* __restrict__ out, int n4) {
  int i = blockIdx.x * blockDim.x + threadIdx.x;
  if (i < n4) {
    float4 v = reinterpret_cast<const float4*>(in)[i];
    ushort4 o;
    o.x = f2bf(v.x); o.y = f2bf(v.y); o.z = f2bf(v.z); o.w = f2bf(v.w);
    reinterpret_cast<ushort4*>(out)[i] = o;
  }
}

// 4 weight matrices in one launch: each 1048576 floats = 262144 float4
__global__ void cvt4_f32_bf16(const float* __restrict__ a, const float* __restrict__ b,
                              const float* __restrict__ c, const float* __restrict__ d,
                              unsigned short* __restrict__ oa, unsigned short* __restrict__ ob,
                              unsigned short* __restrict__ oc, unsigned short* __restrict__ od) {
  int i = blockIdx.x * blockDim.x + threadIdx.x;   // 1048576 total
  int which = i >> 18, j = i & 262143;
  const float* src = (which == 0) ? a : (which == 1) ? b : (which == 2) ? c : d;
  unsigned short* dst = (which == 0) ? oa : (which == 1) ? ob : (which == 2) ? oc : od;
  float4 v = reinterpret_cast<const float4*>(src)[j];
  ushort4 o;
  o.x = f2bf(v.x); o.y = f2bf(v.y); o.z = f2bf(v.z); o.w = f2bf(v.w);
  reinterpret_cast<ushort4*>(dst)[j] = o;
}

// er[128][2048] f32 -> ert[2048][128] bf16, LDS-tiled transpose
__global__ void er_transpose(const float* __restrict__ er, unsigned short* __restrict__ ert) {
  __shared__ float t[32][33];
  int w0 = blockIdx.x * 32, d0 = blockIdx.y * 32;
  int tx = threadIdx.x, ty = threadIdx.y;          // 32 x 8
#pragma unroll
  for (int i = 0; i < 4; ++i)
    t[ty + i * 8][tx] = er[(size_t)(d0 + ty + i * 8) * 2048 + w0 + tx];
  __syncthreads();
#pragma unroll
  for (int i = 0; i < 4; ++i)
    ert[(size_t)(w0 + ty + i * 8) * 128 + d0 + tx] = f2bf(t[tx][ty + i * 8]);
}

// ---------------- GEMM core (shared by qkv-fused and Wo) ----------------
// C[128x128 tile] = A[Mx1024] * Bt[Nx1024]^T + bias.
// mode: 0 bf16 row-major out, 1 bf16 band-transposed Vt out, 2 f32 out.

__device__ __forceinline__ void gemm_tile(
    const unsigned short* __restrict__ A,
    const unsigned short* __restrict__ Bt,
    const float* __restrict__ bias,
    void* __restrict__ C,
    int mode, int i0, int j0,
    unsigned short* lds)
{
  unsigned short* Al = lds;
  unsigned short* Bl = lds + 4096;

  const int tid = threadIdx.x;
  const int lane = tid & 63, wid = tid >> 6;
  const int lr = lane & 15, lq = lane >> 4;
  const int wr = wid >> 1, wc = wid & 1;

  f32x4 acc[4][4] = {};

  const int srow = tid >> 2;
  const int scolb = (tid & 3) << 4;

  const char* Abase = (const char*)A + (size_t)(i0 + srow) * 2048 + scolb;
  const char* Bbase = (const char*)Bt + (size_t)(j0 + srow) * 2048 + scolb;

  for (int kt = 0; kt < 32; ++kt) {
    const int k0b = kt * 64;
    __syncthreads();
    gload_lds16(Abase + k0b,             (char*)Al + tid * 16);
    gload_lds16(Abase + k0b + 64 * 2048, (char*)Al + 4096 + tid * 16);
    gload_lds16(Bbase + k0b,             (char*)Bl + tid * 16);
    gload_lds16(Bbase + k0b + 64 * 2048, (char*)Bl + 4096 + tid * 16);
    __syncthreads();

    bf16x8 af[4], bfr[4];
#pragma unroll
    for (int m = 0; m < 4; ++m)
      af[m] = *(const bf16x8*)((const char*)Al + (wr * 64 + m * 16 + lr) * 64 + lq * 16);
#pragma unroll
    for (int n = 0; n < 4; ++n)
      bfr[n] = *(const bf16x8*)((const char*)Bl + (wc * 64 + n * 16 + lr) * 64 + lq * 16);
    __builtin_amdgcn_s_setprio(1);
#pragma unroll
    for (int m = 0; m < 4; ++m)
#pragma unroll
      for (int n = 0; n < 4; ++n)
        acc[m][n] = mfma_bf16(af[m], bfr[n], acc[m][n]);
    __builtin_amdgcn_s_setprio(0);
  }

  float bv[4];
#pragma unroll
  for (int n = 0; n < 4; ++n) bv[n] = bias[j0 + wc * 64 + n * 16 + lr];

  if (mode == 1) {
    __syncthreads();
#pragma unroll
    for (int m = 0; m < 4; ++m)
#pragma unroll
      for (int n = 0; n < 4; ++n)
#pragma unroll
        for (int r = 0; r < 4; ++r) {
          int il = wr * 64 + m * 16 + lq * 4 + r;
          int jl = wc * 64 + n * 16 + lr;
          lds[jl * 132 + il] = f2bf(acc[m][n][r] + bv[n]);
        }
    __syncthreads();
    const int b = i0 >> 11, w0 = i0 & 2047, bd = j0 >> 7;
    unsigned short* out = (unsigned short*)C;
    for (int idx = tid; idx < 16384; idx += 256) {
      int dl = idx >> 7, wl = idx & 127;
      out[(size_t)((b * 8 + bd) * 128 + dl) * 2048 + w0 + wl] = lds[dl * 132 + wl];
    }
  } else if (mode == 0) {
    unsigned short* out = (unsigned short*)C;
#pragma unroll
    for (int m = 0; m < 4; ++m)
#pragma unroll
      for (int n = 0; n < 4; ++n)
#pragma unroll
        for (int r = 0; r < 4; ++r) {
          int gi = i0 + wr * 64 + m * 16 + lq * 4 + r;
          int gj = j0 + wc * 64 + n * 16 + lr;
          out[(size_t)gi * 1024 + gj] = f2bf(acc[m][n][r] + bv[n]);
        }
  } else {
    float* out = (float*)C;
#pragma unroll
    for (int m = 0; m < 4; ++m)
#pragma unroll
      for (int n = 0; n < 4; ++n)
#pragma unroll
        for (int r = 0; r < 4; ++r) {
          int gi = i0 + wr * 64 + m * 16 + lq * 4 + r;
          int gj = j0 + wc * 64 + n * 16 + lr;
          out[(size_t)gi * 1024 + gj] = acc[m][n][r] + bv[n];
        }
  }
}

// fused Q/K/V projections: grid (32 Mtiles, 24) ; blockIdx.y>>3 selects matrix
__global__ __launch_bounds__(256, 2) void gemm_qkv(
    const unsigned short* __restrict__ xb,
    const unsigned short* __restrict__ Wqb, const unsigned short* __restrict__ Wkb,
    const unsigned short* __restrict__ Wvb,
    const float* __restrict__ bq, const float* __restrict__ bk, const float* __restrict__ bv_,
    unsigned short* __restrict__ Qb, unsigned short* __restrict__ Kb,
    unsigned short* __restrict__ Vtb)
{
  __shared__ unsigned short lds[16896];
  const int which = blockIdx.y >> 3;
  const int i0 = blockIdx.x * 128, j0 = (blockIdx.y & 7) * 128;
  const unsigned short* Bt = (which == 0) ? Wqb : (which == 1) ? Wkb : Wvb;
  const float* bias = (which == 0) ? bq : (which == 1) ? bk : bv_;
  void* C = (which == 0) ? (void*)Qb : (which == 1) ? (void*)Kb : (void*)Vtb;
  gemm_tile(xb, Bt, bias, C, (which == 2) ? 1 : 0, i0, j0, lds);
}

__global__ __launch_bounds__(256, 2) void gemm_bt(
    const unsigned short* __restrict__ A,
    const unsigned short* __restrict__ Bt,
    const float* __restrict__ bias,
    void* __restrict__ C,
    int mode)
{
  __shared__ unsigned short lds[16896];
  gemm_tile(A, Bt, bias, C, mode, blockIdx.x * 128, blockIdx.y * 128, lds);
}

// ---------------- fused attention ----------------
// 128x128 tiles. grid (16 = b*8+band, 16 qtiles), 512 threads (8 waves).
// Counted-vmcnt pipeline: raw s_barrier (no vmcnt drain), global_load_lds
// staging with pre-swizzled global source (linear LDS dest), loads stay in
// flight across barriers.

__global__ __launch_bounds__(512) void attn_fused(
    const unsigned short* __restrict__ Qb,
    const unsigned short* __restrict__ Kb,
    const unsigned short* __restrict__ Vt,
    const unsigned short* __restrict__ ErT,
    float* __restrict__ a_out,
    unsigned short* __restrict__ ctx)
{
  __shared__ __align__(16) char Klb[32768];  // K[kj] [128][256B] swz
  __shared__ __align__(16) char Qlb[32768];  // Q[kj] [128][256B] swz
  __shared__ __align__(16) char Vlb[32768];  // Vt    [128][256B] swz
  __shared__ __align__(16) char Plb[32768];  // P     [128][256B] swz

  const int bb = blockIdx.x;                 // b*8+band
  const int bd = bb & 7, b = bb >> 3;
  const int qi0 = blockIdx.y * 128;
  const int tid = threadIdx.x, wid = tid >> 6, lane = tid & 63;
  const int lr = lane & 15, lq = lane >> 4;

  // persistent A-fragments: Q[qi] and ErT[qi] rows (d=128 -> 4 k-slices)
  bf16x8 qf[4], ef[4];
  {
    const unsigned short* Qrow = Qb + (size_t)(b * 2048 + qi0 + wid * 16 + lr) * 1024 + bd * 128;
    const unsigned short* Erow = ErT + (size_t)(qi0 + wid * 16 + lr) * 128;
#pragma unroll
    for (int kk = 0; kk < 4; ++kk) {
      qf[kk] = *(const bf16x8*)(Qrow + kk * 32 + lq * 8);
      ef[kk] = *(const bf16x8*)(Erow + kk * 32 + lq * 8);
    }
  }

  // staging: linear LDS dest (tid*16), pre-swizzled global source col.
  // LDS slot L -> row = L>>8, cs = L&255 ; data = global(row, cs ^ ((row&7)<<4))
  int ldso[4];
  const char *ksrc[4], *qsrc[4], *vsrc[4];
#pragma unroll
  for (int p = 0; p < 4; ++p) {
    int L = p * 8192 + tid * 16;
    int row = L >> 8, cs = L & 255;
    int sc = cs ^ ((row & 7) << 4);
    ldso[p] = L;
    ksrc[p] = (const char*)Kb + ((size_t)(b * 2048 + row) * 1024 + bd * 128) * 2 + sc;
    qsrc[p] = (const char*)Qb + ((size_t)(b * 2048 + row) * 1024 + bd * 128) * 2 + sc;
    vsrc[p] = (const char*)Vt + ((size_t)(bb * 128 + row) * 2048) * 2 + sc;
  }

  // prologue: issue tile-0 staging (12 loads in flight)
#pragma unroll
  for (int p = 0; p < 4; ++p) gload_lds16(ksrc[p], Klb + ldso[p]);
#pragma unroll
  for (int p = 0; p < 4; ++p) gload_lds16(qsrc[p], Qlb + ldso[p]);
#pragma unroll
  for (int p = 0; p < 4; ++p) gload_lds16(vsrc[p], Vlb + ldso[p]);

  f32x4 oacc[8] = {};
  float M[4], L[4];
#pragma unroll
  for (int r = 0; r < 4; ++r) { M[r] = -1e30f; L[r] = 0.f; }

  float* abase = a_out + (size_t)bb * 2048 * 2048;

  for (int kt = 0; kt < 16; ++kt) {
    const int kj0 = kt * 128;
    const size_t nkq = (size_t)((kt + 1) & 15) * 262144;  // +128 rows * 2048B
    const size_t nv = (size_t)((kt + 1) & 15) * 256;      // +128 cols * 2B

    // own KQ(t) landed (V(t) may still fly); then all-waves rendezvous
    asm volatile("s_waitcnt vmcnt(4)" ::: "memory");
    __builtin_amdgcn_sched_barrier(0);
    __builtin_amdgcn_s_barrier();
    __builtin_amdgcn_sched_barrier(0);

    // S = Q·K^T + ErT·Qk^T
    f32x4 sacc[8] = {};
    __builtin_amdgcn_s_setprio(1);
#pragma unroll
    for (int kk = 0; kk < 4; ++kk) {
#pragma unroll
      for (int nf = 0; nf < 8; ++nf) {
        const int row = nf * 16 + lr;
        bf16x8 kf = *(const bf16x8*)(Klb + row * 256 + ((kk * 64 + lq * 16) ^ ((row & 7) << 4)));
        sacc[nf] = mfma_bf16(qf[kk], kf, sacc[nf]);
      }
#pragma unroll
      for (int nf = 0; nf < 8; ++nf) {
        const int row = nf * 16 + lr;
        bf16x8 qkf = *(const bf16x8*)(Qlb + row * 256 + ((kk * 64 + lq * 16) ^ ((row & 7) << 4)));
        sacc[nf] = mfma_bf16(ef[kk], qkf, sacc[nf]);
      }
    }
    __builtin_amdgcn_s_setprio(0);

    __builtin_amdgcn_sched_barrier(0);
    __builtin_amdgcn_s_barrier();        // all waves done reading Klb/Qlb
    __builtin_amdgcn_sched_barrier(0);

    // scale and emit `a` (plain stores through L2, full-row-burst coverage)
#pragma unroll
    for (int nf = 0; nf < 8; ++nf)
#pragma unroll
      for (int r = 0; r < 4; ++r) sacc[nf][r] *= 0.03125f;
    {
      const int qrow_base = qi0 + wid * 16 + lq * 4;
#pragma unroll
      for (int nf = 0; nf < 8; ++nf)
#pragma unroll
        for (int r = 0; r < 4; ++r)
          abase[(size_t)(qrow_base + r) * 2048 + kj0 + nf * 16 + lr] = sacc[nf][r];
    }

    // issue K,Q staging for t+1 (after all a-stores; pinned)
    __builtin_amdgcn_sched_barrier(0);
#pragma unroll
    for (int p = 0; p < 4; ++p) gload_lds16(ksrc[p] + nkq, Klb + ldso[p]);
#pragma unroll
    for (int p = 0; p < 4; ++p) gload_lds16(qsrc[p] + nkq, Qlb + ldso[p]);
    __builtin_amdgcn_sched_barrier(0);

    // online softmax with defer-max
    float rmax[4];
#pragma unroll
    for (int r = 0; r < 4; ++r) {
      float m0 = sacc[0][r];
#pragma unroll
      for (int nf = 1; nf < 8; ++nf) m0 = fmaxf(m0, sacc[nf][r]);
      m0 = fmaxf(m0, __shfl_xor(m0, 1));
      m0 = fmaxf(m0, __shfl_xor(m0, 2));
      m0 = fmaxf(m0, __shfl_xor(m0, 4));
      m0 = fmaxf(m0, __shfl_xor(m0, 8));
      rmax[r] = m0;
    }
    bool small = (rmax[0] - M[0] <= 8.f) & (rmax[1] - M[1] <= 8.f) &
                 (rmax[2] - M[2] <= 8.f) & (rmax[3] - M[3] <= 8.f);
    unsigned long long vote = __ballot(small);
    if (vote != ~0ull) {
      float scl[4];
#pragma unroll
      for (int r = 0; r < 4; ++r) {
        float Mn = fmaxf(M[r], rmax[r]);
        scl[r] = __expf(M[r] - Mn);
        M[r] = Mn;
        L[r] *= scl[r];
      }
#pragma unroll
      for (int dn = 0; dn < 8; ++dn)
#pragma unroll
        for (int r = 0; r < 4; ++r) oacc[dn][r] *= scl[r];
    }
    float rsum[4] = {0.f, 0.f, 0.f, 0.f};
#pragma unroll
    for (int nf = 0; nf < 8; ++nf)
#pragma unroll
      for (int r = 0; r < 4; ++r) {
        float pv = __expf(sacc[nf][r] - M[r]);
        sacc[nf][r] = pv;
        rsum[r] += pv;
      }
    // P -> LDS (bf16), wave-local rows, swizzled
    {
      const int prow0 = wid * 16 + lq * 4;
#pragma unroll
      for (int nf = 0; nf < 8; ++nf)
#pragma unroll
        for (int r = 0; r < 4; ++r) {
          const int row = prow0 + r;
          *(unsigned short*)(Plb + row * 256 + (((nf * 16 + lr) * 2) ^ ((row & 7) << 4))) =
              f2bf(sacc[nf][r]);
        }
    }
#pragma unroll
    for (int r = 0; r < 4; ++r) {
      rsum[r] += __shfl_xor(rsum[r], 1);
      rsum[r] += __shfl_xor(rsum[r], 2);
      rsum[r] += __shfl_xor(rsum[r], 4);
      rsum[r] += __shfl_xor(rsum[r], 8);
      L[r] += rsum[r];
    }

    // V(t) landed (stores drained too; KQ(t+1) still flying)
    asm volatile("s_waitcnt vmcnt(8)" ::: "memory");
    __builtin_amdgcn_sched_barrier(0);

    // O += P · V
    __builtin_amdgcn_s_setprio(1);
#pragma unroll
    for (int kk = 0; kk < 4; ++kk) {
      const int prow = wid * 16 + lr;
      bf16x8 pf = *(const bf16x8*)(Plb + prow * 256 + ((kk * 64 + lq * 16) ^ ((prow & 7) << 4)));
#pragma unroll
      for (int dn = 0; dn < 8; ++dn) {
        const int vrow = dn * 16 + lr;
        bf16x8 vf = *(const bf16x8*)(Vlb + vrow * 256 + ((kk * 64 + lq * 16) ^ ((vrow & 7) << 4)));
        oacc[dn] = mfma_bf16(pf, vf, oacc[dn]);
      }
    }
    __builtin_amdgcn_s_setprio(0);

    __builtin_amdgcn_sched_barrier(0);
    __builtin_amdgcn_s_barrier();        // all waves done reading Vlb
    __builtin_amdgcn_sched_barrier(0);
#pragma unroll
    for (int p = 0; p < 4; ++p) gload_lds16(vsrc[p] + nv, Vlb + ldso[p]);
    __builtin_amdgcn_sched_barrier(0);
  }

  // epilogue: ctx = O / L -> bf16 [b*2048+w][bd*128+d]
  {
    const int qrow_base = b * 2048 + qi0 + wid * 16 + lq * 4;
#pragma unroll
    for (int dn = 0; dn < 8; ++dn)
#pragma unroll
      for (int r = 0; r < 4; ++r) {
        float v = oacc[dn][r] / L[r];
        ctx[(size_t)(qrow_base + r) * 1024 + bd * 128 + dn * 16 + lr] = f2bf(v);
      }
  }
}

// ---------------- launch ----------------

extern "C" void kernel_launch(void* const* d_in, const int* in_sizes, int n_in,
                              void* d_out, int out_size, void* d_ws, size_t ws_size,
                              hipStream_t stream) {
  const float* x  = (const float*)d_in[0];
  const float* Wq = (const float*)d_in[1];
  const float* bq = (const float*)d_in[2];
  const float* Wk = (const float*)d_in[3];
  const float* bk = (const float*)d_in[4];
  const float* Wv = (const float*)d_in[5];
  const float* bv = (const float*)d_in[6];
  const float* Wo = (const float*)d_in[7];
  const float* bo = (const float*)d_in[8];
  const float* er = (const float*)d_in[9];

  char* ws = (char*)d_ws;
  unsigned short* xb  = (unsigned short*)(ws + 0);          //  8 MB
  unsigned short* Wqb = (unsigned short*)(ws + 8388608);    //  2 MB
  unsigned short* Wkb = (unsigned short*)(ws + 10485760);   //  2 MB
  unsigned short* Wvb = (unsigned short*)(ws + 12582912);   //  2 MB
  unsigned short* Wob = (unsigned short*)(ws + 14680064);   //  2 MB
  unsigned short* Qb  = (unsigned short*)(ws + 16777216);   //  8 MB
  unsigned short* Kb  = (unsigned short*)(ws + 25165824);   //  8 MB
  unsigned short* Vtb = (unsigned short*)(ws + 33554432);   //  8 MB [16][128][2048]
  unsigned short* ctx = (unsigned short*)(ws + 41943040);   //  8 MB
  unsigned short* ert = (unsigned short*)(ws + 50331648);   //  0.5 MB [2048][128]

  float* a_out = (float*)d_out + 4194304;

  cvt_f32_bf16<<<dim3(4096), dim3(256), 0, stream>>>(x, xb, 1048576);
  cvt4_f32_bf16<<<dim3(4096), dim3(256), 0, stream>>>(Wq, Wk, Wv, Wo, Wqb, Wkb, Wvb, Wob);
  er_transpose<<<dim3(64, 4), dim3(32, 8), 0, stream>>>(er, ert);

  gemm_qkv<<<dim3(32, 24), dim3(256), 0, stream>>>(xb, Wqb, Wkb, Wvb, bq, bk, bv,
                                                   Qb, Kb, Vtb);

  attn_fused<<<dim3(16, 16), dim3(512), 0, stream>>>(Qb, Kb, Vtb, ert, a_out, ctx);

  gemm_bt<<<dim3(32, 8), dim3(256), 0, stream>>>(ctx, Wob, bo, d_out, 2);
}